// Round 1
// baseline (1395.253 us; speedup 1.0000x reference)
//
#include <hip/hip_runtime.h>
#include <math.h>

#define NCH 96      // B*C = 32*3
#define HH 512
#define WW 512
#define OH 502      // valid output rows/cols (512 - 10)
#define STRIP 64    // output rows per block
#define NSTRIP 8    // ceil(502/64)
#define NT 256      // threads per block, 2 columns each

struct Win { float w[11]; };

__device__ __forceinline__ float ssim_px(float m1, float m2, float ms, float mp) {
    const float C1v = 1e-4f;   // (0.01*1.0)^2
    const float C2v = 9e-4f;   // (0.03*1.0)^2
    float mu12  = m1 * m2;
    float musum = fmaf(m1, m1, m2 * m2);              // mu1^2 + mu2^2
    // ssim = (2*mu12+C1)(2*sigma12+C2) / ((musum+C1)(sigmasum+C2))
    float num = fmaf(2.f, mp - mu12, C2v) * fmaf(2.f, mu12, C1v);
    float den = ((ms - musum) + C2v) * (musum + C1v); // > 0 always
    return num * __builtin_amdgcn_rcpf(den);
}

// horizontal polyphase: output col 2t uses E[t..t+5] (w0,w2,..,w10) and O[t..t+4] (w1,..,w9)
//                       output col 2t+1 uses O[t..t+5] (w0,w2,..,w10) and E[t+1..t+5] (w1,..,w9)
#define HB_A(f) (w0*e0.f + w1*o0.f + w2*e1.f + w3*o1.f + w4*e2.f + w5*o2.f \
               + w6*e3.f + w7*o3.f + w8*e4.f + w9*o4.f + w10*e5.f)
#define HB_B(f) (w0*o0.f + w1*e1.f + w2*o1.f + w3*e2.f + w4*o2.f + w5*e3.f \
               + w6*o3.f + w7*e4.f + w8*o4.f + w9*e5.f + w10*o5.f)

__global__ __launch_bounds__(NT, 3)
void ssim_main(const float* __restrict__ X, const float* __restrict__ Y,
               float* __restrict__ partial, Win win) {
    __shared__ float4 Eb[2][256];   // even columns, vblur row (vx,vy,vs,vp)
    __shared__ float4 Ob[2][256];   // odd columns
    __shared__ float red[4];

    const int b     = blockIdx.x;
    const int ch    = b >> 3;         // / NSTRIP
    const int strip = b & 7;
    const int r0    = strip * STRIP;
    const int rows  = min(STRIP, OH - r0);
    const int t     = threadIdx.x;

    const size_t choff = (size_t)ch * (HH * WW);
    const float* xrow = X + choff + 2 * t;   // column base
    const float* yrow = Y + choff + 2 * t;

    // 11-row circular buffers (register resident; all indices static after unroll)
    float ax[11], ay[11], as_[11], ap[11];   // even col quantities
    float bx[11], by[11], bs_[11], bp[11];   // odd col quantities

    #pragma unroll
    for (int i = 0; i < 10; ++i) {
        float2 xv = *(const float2*)(xrow + (size_t)(r0 + i) * WW);
        float2 yv = *(const float2*)(yrow + (size_t)(r0 + i) * WW);
        float x0 = fmaf(xv.x, 0.5f, 0.5f), x1 = fmaf(xv.y, 0.5f, 0.5f);
        float y0 = fmaf(yv.x, 0.5f, 0.5f), y1 = fmaf(yv.y, 0.5f, 0.5f);
        ax[i] = x0; ay[i] = y0; as_[i] = fmaf(x0, x0, y0 * y0); ap[i] = x0 * y0;
        bx[i] = x1; by[i] = y1; bs_[i] = fmaf(x1, x1, y1 * y1); bp[i] = x1 * y1;
    }
    // held (prefetched) raw row r0+10
    float2 hx = *(const float2*)(xrow + (size_t)(r0 + 10) * WW);
    float2 hy = *(const float2*)(yrow + (size_t)(r0 + 10) * WW);

    float acc = 0.f;
    int r = 0, buf = 0;

    while (r < rows) {
        #pragma unroll
        for (int p = 0; p < 11; ++p) {
            if (r < rows) {
                // insert held row into slot (p+10)%11
                {
                    const int s = (p + 10) % 11;
                    float x0 = fmaf(hx.x, 0.5f, 0.5f), x1 = fmaf(hx.y, 0.5f, 0.5f);
                    float y0 = fmaf(hy.x, 0.5f, 0.5f), y1 = fmaf(hy.y, 0.5f, 0.5f);
                    ax[s] = x0; ay[s] = y0; as_[s] = fmaf(x0, x0, y0 * y0); ap[s] = x0 * y0;
                    bx[s] = x1; by[s] = y1; bs_[s] = fmaf(x1, x1, y1 * y1); bp[s] = x1 * y1;
                }
                // vertical blur (output row r uses slots (p+k)%11, k=0..10)
                float vxA = 0.f, vyA = 0.f, vsA = 0.f, vpA = 0.f;
                float vxB = 0.f, vyB = 0.f, vsB = 0.f, vpB = 0.f;
                #pragma unroll
                for (int k = 0; k < 11; ++k) {
                    const int s = (p + k) % 11;
                    const float wk = win.w[k];
                    vxA = fmaf(wk, ax[s], vxA); vyA = fmaf(wk, ay[s], vyA);
                    vsA = fmaf(wk, as_[s], vsA); vpA = fmaf(wk, ap[s], vpA);
                    vxB = fmaf(wk, bx[s], vxB); vyB = fmaf(wk, by[s], vyB);
                    vsB = fmaf(wk, bs_[s], vsB); vpB = fmaf(wk, bp[s], vpB);
                }
                Eb[buf][t] = make_float4(vxA, vyA, vsA, vpA);
                Ob[buf][t] = make_float4(vxB, vyB, vsB, vpB);
                // prefetch next raw row (clamped; clamped value is never consumed)
                {
                    const int g = min(r0 + r + 11, HH - 1);
                    hx = *(const float2*)(xrow + (size_t)g * WW);
                    hy = *(const float2*)(yrow + (size_t)g * WW);
                }
                __syncthreads();
                // horizontal blur + ssim for output cols 2t, 2t+1 (only 0..501 valid)
                if (t <= 250) {
                    const float4* Ep = Eb[buf];
                    const float4* Op = Ob[buf];
                    float4 e0 = Ep[t],     e1 = Ep[t + 1], e2 = Ep[t + 2];
                    float4 e3 = Ep[t + 3], e4 = Ep[t + 4], e5 = Ep[t + 5];
                    float4 o0 = Op[t],     o1 = Op[t + 1], o2 = Op[t + 2];
                    float4 o3 = Op[t + 3], o4 = Op[t + 4], o5 = Op[t + 5];
                    const float w0 = win.w[0], w1 = win.w[1], w2 = win.w[2], w3 = win.w[3];
                    const float w4 = win.w[4], w5 = win.w[5], w6 = win.w[6], w7 = win.w[7];
                    const float w8 = win.w[8], w9 = win.w[9], w10 = win.w[10];
                    float A1 = HB_A(x), A2 = HB_A(y), As = HB_A(z), Ap = HB_A(w);
                    float B1 = HB_B(x), B2 = HB_B(y), Bs = HB_B(z), Bp = HB_B(w);
                    acc += ssim_px(A1, A2, As, Ap);
                    acc += ssim_px(B1, B2, Bs, Bp);
                }
                buf ^= 1;
                ++r;
            }
        }
    }

    // block reduction -> one partial per block (no atomics: deterministic)
    #pragma unroll
    for (int m = 1; m < 64; m <<= 1) acc += __shfl_xor(acc, m, 64);
    __syncthreads();
    if ((t & 63) == 0) red[t >> 6] = acc;
    __syncthreads();
    if (t == 0) partial[b] = (red[0] + red[1]) + (red[2] + red[3]);
}

__global__ __launch_bounds__(128)
void ssim_final(const float* __restrict__ partial, float* __restrict__ out) {
    const int t = threadIdx.x;  // 128 threads
    float v = 0.f;
    if (t < NCH) {
        float s = 0.f;
        #pragma unroll
        for (int i = 0; i < NSTRIP; ++i) s += partial[t * NSTRIP + i];
        s *= (1.f / (502.f * 502.f));   // per-channel spatial mean
        v = fmaxf(s, 0.f);              // relu (nonnegative_ssim)
    }
    #pragma unroll
    for (int m = 1; m < 64; m <<= 1) v += __shfl_xor(v, m, 64);
    __shared__ float r2[2];
    if ((t & 63) == 0) r2[t >> 6] = v;
    __syncthreads();
    if (t == 0) out[0] = 1.f - (r2[0] + r2[1]) * (1.f / (float)NCH);
}

extern "C" void kernel_launch(void* const* d_in, const int* in_sizes, int n_in,
                              void* d_out, int out_size, void* d_ws, size_t ws_size,
                              hipStream_t stream) {
    const float* X = (const float*)d_in[0];
    const float* Y = (const float*)d_in[1];
    float* out = (float*)d_out;
    float* partial = (float*)d_ws;   // NCH*NSTRIP = 768 floats

    Win win;
    double g[11], sum = 0.0;
    for (int i = 0; i < 11; ++i) {
        double c = (double)(i - 5);
        g[i] = exp(-(c * c) / (2.0 * 1.5 * 1.5));
        sum += g[i];
    }
    for (int i = 0; i < 11; ++i) win.w[i] = (float)(g[i] / sum);

    ssim_main<<<NCH * NSTRIP, NT, 0, stream>>>(X, Y, partial, win);
    ssim_final<<<1, 128, 0, stream>>>(partial, out);
}

// Round 2
// 140.580 us; speedup vs baseline: 9.9250x; 9.9250x over previous
//
#include <hip/hip_runtime.h>
#include <math.h>

#define NCH 96      // B*C = 32*3
#define HH 512
#define WW 512
#define OH 502      // valid output rows/cols (512 - 10)
#define STRIP 64    // output rows per block
#define NSTRIP 8    // ceil(502/64)
#define NT 256      // threads per block, 2 columns each

struct Win { float w[11]; };

__device__ __forceinline__ float ssim_px(float m1, float m2, float ms, float mp) {
    const float C1v = 1e-4f;   // (0.01*1.0)^2
    const float C2v = 9e-4f;   // (0.03*1.0)^2
    float mu12  = m1 * m2;
    float musum = fmaf(m1, m1, m2 * m2);              // mu1^2 + mu2^2
    float num = fmaf(2.f, mp - mu12, C2v) * fmaf(2.f, mu12, C1v);
    float den = ((ms - musum) + C2v) * (musum + C1v); // > 0 always
    return num * __builtin_amdgcn_rcpf(den);
}

// horizontal polyphase: output col 2t uses E[t..t+5] (w0,w2,..,w10) and O[t..t+4] (w1,..,w9)
//                       output col 2t+1 uses O[t..t+5] (w0,w2,..,w10) and E[t+1..t+5] (w1,..,w9)
#define HB_A(f) (w0*e0.f + w1*o0.f + w2*e1.f + w3*o1.f + w4*e2.f + w5*o2.f \
               + w6*e3.f + w7*o3.f + w8*e4.f + w9*o4.f + w10*e5.f)
#define HB_B(f) (w0*o0.f + w1*e1.f + w2*o1.f + w3*e2.f + w4*o2.f + w5*e3.f \
               + w6*o3.f + w7*e4.f + w8*o4.f + w9*e5.f + w10*o5.f)

__global__ __launch_bounds__(NT, 3)
void ssim_main(const float* __restrict__ X, const float* __restrict__ Y,
               float* __restrict__ partial, Win win) {
    __shared__ float4 Eb[2][256];   // even columns, vblur row (vx,vy,vs,vp)
    __shared__ float4 Ob[2][256];   // odd columns
    __shared__ float red[4];

    const int b     = blockIdx.x;
    const int ch    = b >> 3;         // / NSTRIP
    const int strip = b & 7;
    const int r0    = strip * STRIP;
    const int rows  = min(STRIP, OH - r0);
    const int t     = threadIdx.x;

    const size_t choff = (size_t)ch * (HH * WW);
    const float* xcol = X + choff + 2 * t;   // column-pair base
    const float* ycol = Y + choff + 2 * t;

    // 10-slot shift registers of NORMALIZED values, all indices static.
    // Slot i holds row r+i for current output row r. Tap 10 comes from `held`.
    float axv[10], ayv[10], bxv[10], byv[10];

    #pragma unroll
    for (int i = 0; i < 10; ++i) {
        float2 xv = *(const float2*)(xcol + (size_t)(r0 + i) * WW);
        float2 yv = *(const float2*)(ycol + (size_t)(r0 + i) * WW);
        axv[i] = fmaf(xv.x, 0.5f, 0.5f); bxv[i] = fmaf(xv.y, 0.5f, 0.5f);
        ayv[i] = fmaf(yv.x, 0.5f, 0.5f); byv[i] = fmaf(yv.y, 0.5f, 0.5f);
    }
    // held raw row r0+10
    float2 hx = *(const float2*)(xcol + (size_t)(r0 + 10) * WW);
    float2 hy = *(const float2*)(ycol + (size_t)(r0 + 10) * WW);

    float acc = 0.f;

    for (int r = 0; r < rows; ++r) {
        const int buf = r & 1;
        // normalize held row (tap 10)
        const float nax = fmaf(hx.x, 0.5f, 0.5f), nbx = fmaf(hx.y, 0.5f, 0.5f);
        const float nay = fmaf(hy.x, 0.5f, 0.5f), nby = fmaf(hy.y, 0.5f, 0.5f);

        // vertical blur; s = x*x+y*y and p = x*y computed on the fly
        float vxA, vyA, vsA, vpA, vxB, vyB, vsB, vpB;
        {
            const float wk = win.w[10];
            vxA = wk * nax; vyA = wk * nay;
            vsA = wk * fmaf(nax, nax, nay * nay); vpA = wk * (nax * nay);
            vxB = wk * nbx; vyB = wk * nby;
            vsB = wk * fmaf(nbx, nbx, nby * nby); vpB = wk * (nbx * nby);
        }
        #pragma unroll
        for (int k = 0; k < 10; ++k) {
            const float wk = win.w[k];
            const float xa = axv[k], ya = ayv[k], xb = bxv[k], yb = byv[k];
            vxA = fmaf(wk, xa, vxA); vyA = fmaf(wk, ya, vyA);
            vsA = fmaf(wk, fmaf(xa, xa, ya * ya), vsA); vpA = fmaf(wk, xa * ya, vpA);
            vxB = fmaf(wk, xb, vxB); vyB = fmaf(wk, yb, vyB);
            vsB = fmaf(wk, fmaf(xb, xb, yb * yb), vsB); vpB = fmaf(wk, xb * yb, vpB);
        }
        Eb[buf][t] = make_float4(vxA, vyA, vsA, vpA);
        Ob[buf][t] = make_float4(vxB, vyB, vsB, vpB);

        // shift by one row; append normalized held
        #pragma unroll
        for (int k = 0; k < 9; ++k) {
            axv[k] = axv[k + 1]; ayv[k] = ayv[k + 1];
            bxv[k] = bxv[k + 1]; byv[k] = byv[k + 1];
        }
        axv[9] = nax; ayv[9] = nay; bxv[9] = nbx; byv[9] = nby;

        // prefetch next raw row (clamped; clamped value is never consumed)
        {
            const int g = min(r0 + r + 11, HH - 1);
            hx = *(const float2*)(xcol + (size_t)g * WW);
            hy = *(const float2*)(ycol + (size_t)g * WW);
        }

        __syncthreads();
        // horizontal blur + ssim for output cols 2t, 2t+1 (only 0..501 valid)
        if (t <= 250) {
            const float4* Ep = Eb[buf];
            const float4* Op = Ob[buf];
            float4 e0 = Ep[t],     e1 = Ep[t + 1], e2 = Ep[t + 2];
            float4 e3 = Ep[t + 3], e4 = Ep[t + 4], e5 = Ep[t + 5];
            float4 o0 = Op[t],     o1 = Op[t + 1], o2 = Op[t + 2];
            float4 o3 = Op[t + 3], o4 = Op[t + 4], o5 = Op[t + 5];
            const float w0 = win.w[0], w1 = win.w[1], w2 = win.w[2], w3 = win.w[3];
            const float w4 = win.w[4], w5 = win.w[5], w6 = win.w[6], w7 = win.w[7];
            const float w8 = win.w[8], w9 = win.w[9], w10 = win.w[10];
            float A1 = HB_A(x), A2 = HB_A(y), As = HB_A(z), Ap = HB_A(w);
            float B1 = HB_B(x), B2 = HB_B(y), Bs = HB_B(z), Bp = HB_B(w);
            acc += ssim_px(A1, A2, As, Ap);
            acc += ssim_px(B1, B2, Bs, Bp);
        }
    }

    // block reduction -> one partial per block (no atomics: deterministic)
    #pragma unroll
    for (int m = 1; m < 64; m <<= 1) acc += __shfl_xor(acc, m, 64);
    __syncthreads();
    if ((t & 63) == 0) red[t >> 6] = acc;
    __syncthreads();
    if (t == 0) partial[b] = (red[0] + red[1]) + (red[2] + red[3]);
}

__global__ __launch_bounds__(128)
void ssim_final(const float* __restrict__ partial, float* __restrict__ out) {
    const int t = threadIdx.x;  // 128 threads
    float v = 0.f;
    if (t < NCH) {
        float s = 0.f;
        #pragma unroll
        for (int i = 0; i < NSTRIP; ++i) s += partial[t * NSTRIP + i];
        s *= (1.f / (502.f * 502.f));   // per-channel spatial mean
        v = fmaxf(s, 0.f);              // relu (nonnegative_ssim)
    }
    #pragma unroll
    for (int m = 1; m < 64; m <<= 1) v += __shfl_xor(v, m, 64);
    __shared__ float r2[2];
    if ((t & 63) == 0) r2[t >> 6] = v;
    __syncthreads();
    if (t == 0) out[0] = 1.f - (r2[0] + r2[1]) * (1.f / (float)NCH);
}

extern "C" void kernel_launch(void* const* d_in, const int* in_sizes, int n_in,
                              void* d_out, int out_size, void* d_ws, size_t ws_size,
                              hipStream_t stream) {
    const float* X = (const float*)d_in[0];
    const float* Y = (const float*)d_in[1];
    float* out = (float*)d_out;
    float* partial = (float*)d_ws;   // NCH*NSTRIP = 768 floats

    Win win;
    double g[11], sum = 0.0;
    for (int i = 0; i < 11; ++i) {
        double c = (double)(i - 5);
        g[i] = exp(-(c * c) / (2.0 * 1.5 * 1.5));
        sum += g[i];
    }
    for (int i = 0; i < 11; ++i) win.w[i] = (float)(g[i] / sum);

    ssim_main<<<NCH * NSTRIP, NT, 0, stream>>>(X, Y, partial, win);
    ssim_final<<<1, 128, 0, stream>>>(partial, out);
}